// Round 1
// baseline (1959.252 us; speedup 1.0000x reference)
//
#include <hip/hip_runtime.h>

#define T_N 4096
#define B_N 64
#define I_N 128
#define H_N 128
#define BH  (B_N * H_N)

// ---------------------------------------------------------------------------
// Phase 1: xp[t,b,:] = x[t,b,:] @ W_ih^T + b_ih  -> written into out[0..T*B*H)
// (the hs region; phase 2 reads it and overwrites with h_t in place).
// Grid: (T*B/64) blocks x 256 threads. Per block: 64 rows x 128 cols.
// W_ih is staged TRANSPOSED in exactly 64 KB static LDS (wt[k][j]); x rows
// are read via L1 (4 distinct broadcast addresses per wave-inst).
// ---------------------------------------------------------------------------
__global__ __launch_bounds__(256) void xproj_kernel(
    const float* __restrict__ x, const float* __restrict__ Wih,
    const float* __restrict__ bih, float* __restrict__ xp)
{
    __shared__ float wt[I_N][H_N];   // wt[k][j] = Wih[j][k], 64 KB
    const int tid = threadIdx.x;

    // Stage transposed W. i = tid*16+it => row r = tid>>1 per thread, so each
    // ds_write_b32 has 32 distinct banks across the wave (2-way = free).
    {
        const float4* w4 = (const float4*)Wih;
        #pragma unroll
        for (int it = 0; it < 16; ++it) {
            int i = tid * 16 + it;          // 0..4095 float4s
            float4 v = w4[i];
            int r = i >> 5;                 // W row j
            int k = (i & 31) << 2;          // k base
            wt[k + 0][r] = v.x;
            wt[k + 1][r] = v.y;
            wt[k + 2][r] = v.z;
            wt[k + 3][r] = v.w;
        }
    }
    __syncthreads();

    const int  tx   = tid & 15;             // cols: tx*8 + cc, cc = 0..7
    const int  ty   = tid >> 4;             // rows: ty*4 + r,  r  = 0..3
    const long row0 = (long)blockIdx.x * 64;
    const float* xbase = x + (row0 + ty * 4) * I_N;

    float acc[4][8];
    #pragma unroll
    for (int r = 0; r < 4; ++r)
        #pragma unroll
        for (int c = 0; c < 8; ++c) acc[r][c] = 0.0f;

    #pragma unroll 4
    for (int k4 = 0; k4 < I_N / 4; ++k4) {
        float4 xv[4];
        #pragma unroll
        for (int r = 0; r < 4; ++r)
            xv[r] = *(const float4*)(xbase + r * I_N + k4 * 4);

        #pragma unroll
        for (int kk = 0; kk < 4; ++kk) {
            int k = k4 * 4 + kk;
            float4 w0 = *(const float4*)&wt[k][tx * 8];
            float4 w1 = *(const float4*)&wt[k][tx * 8 + 4];
            #pragma unroll
            for (int r = 0; r < 4; ++r) {
                float xk = ((const float*)&xv[r])[kk];   // static after unroll
                acc[r][0] = fmaf(xk, w0.x, acc[r][0]);
                acc[r][1] = fmaf(xk, w0.y, acc[r][1]);
                acc[r][2] = fmaf(xk, w0.z, acc[r][2]);
                acc[r][3] = fmaf(xk, w0.w, acc[r][3]);
                acc[r][4] = fmaf(xk, w1.x, acc[r][4]);
                acc[r][5] = fmaf(xk, w1.y, acc[r][5]);
                acc[r][6] = fmaf(xk, w1.z, acc[r][6]);
                acc[r][7] = fmaf(xk, w1.w, acc[r][7]);
            }
        }
    }

    float4 b0 = *(const float4*)(bih + tx * 8);
    float4 b1 = *(const float4*)(bih + tx * 8 + 4);
    #pragma unroll
    for (int r = 0; r < 4; ++r) {
        long row = row0 + ty * 4 + r;
        float4 o0, o1;
        o0.x = acc[r][0] + b0.x;  o0.y = acc[r][1] + b0.y;
        o0.z = acc[r][2] + b0.z;  o0.w = acc[r][3] + b0.w;
        o1.x = acc[r][4] + b1.x;  o1.y = acc[r][5] + b1.y;
        o1.z = acc[r][6] + b1.z;  o1.w = acc[r][7] + b1.w;
        *(float4*)(xp + row * H_N + tx * 8)     = o0;
        *(float4*)(xp + row * H_N + tx * 8 + 4) = o1;
    }
}

// ---------------------------------------------------------------------------
// Phase 2: sequential scan. One block per batch element b (64 blocks, 256 thr).
// Thread (p = tid&1, j = tid>>1) owns half of W_hh row j in registers
// (64 floats = 16 float4, contiguous chunk at W_hh + tid*64).
// h double-buffered in LDS; dot split across the lane pair, combined via
// __shfl_xor(.,1); xp prefetched 4 steps ahead; h_t written in place over xp.
// ---------------------------------------------------------------------------
__global__ __launch_bounds__(256) void scan_kernel(
    const float* __restrict__ Whh, const float* __restrict__ bhh,
    const float* __restrict__ h0, float* __restrict__ out)
{
    const int tid = threadIdx.x;
    const int b   = blockIdx.x;
    const int p   = tid & 1;
    const int j   = tid >> 1;
    __shared__ float hbuf[2][H_N];

    float4 w[16];
    {
        const float4* wsrc = (const float4*)(Whh + tid * 64);
        #pragma unroll
        for (int c = 0; c < 16; ++c) w[c] = wsrc[c];
    }
    const float bh = bhh[j];

    if (tid < H_N) hbuf[0][tid] = h0[b * H_N + tid];

    const float* xq = out + b * H_N + j;   // xp element (t,b,j) at xq[t*BH]
    float*       oq = out + b * H_N + j;

    float xv0 = xq[(size_t)0 * BH];
    float xv1 = xq[(size_t)1 * BH];
    float xv2 = xq[(size_t)2 * BH];
    float xv3 = xq[(size_t)3 * BH];
    __syncthreads();

#define RNN_STEP(T0, XV, CUR) do {                                            \
        const float4* hb = (const float4*)(&hbuf[CUR][0]) + p * 16;           \
        float s0 = 0.f, s1 = 0.f, s2 = 0.f, s3 = 0.f;                         \
        _Pragma("unroll")                                                     \
        for (int c = 0; c < 16; ++c) {                                        \
            float4 hv = hb[c];                                                \
            s0 = fmaf(w[c].x, hv.x, s0);                                      \
            s1 = fmaf(w[c].y, hv.y, s1);                                      \
            s2 = fmaf(w[c].z, hv.z, s2);                                      \
            s3 = fmaf(w[c].w, hv.w, s3);                                      \
        }                                                                     \
        float part = (s0 + s1) + (s2 + s3);                                   \
        part += __shfl_xor(part, 1);                                          \
        float full = part + (XV) + bh;                                        \
        float e  = __expf(2.0f * full);                                       \
        float th = 1.0f - 2.0f * __builtin_amdgcn_rcpf(e + 1.0f);             \
        if (p == 0) {                                                         \
            hbuf[(CUR) ^ 1][j] = th;                                          \
            oq[(size_t)(T0) * BH] = th;                                       \
            if ((T0) == T_N - 1) oq[(size_t)T_N * BH] = th;                   \
        }                                                                     \
        __syncthreads();                                                      \
    } while (0)

    for (int t = 0; t < T_N; t += 4) {
        RNN_STEP(t + 0, xv0, 0);
        xv0 = (t + 4 < T_N) ? xq[(size_t)(t + 4) * BH] : 0.f;
        RNN_STEP(t + 1, xv1, 1);
        xv1 = (t + 5 < T_N) ? xq[(size_t)(t + 5) * BH] : 0.f;
        RNN_STEP(t + 2, xv2, 0);
        xv2 = (t + 6 < T_N) ? xq[(size_t)(t + 6) * BH] : 0.f;
        RNN_STEP(t + 3, xv3, 1);
        xv3 = (t + 7 < T_N) ? xq[(size_t)(t + 7) * BH] : 0.f;
    }
#undef RNN_STEP
}

extern "C" void kernel_launch(void* const* d_in, const int* in_sizes, int n_in,
                              void* d_out, int out_size, void* d_ws, size_t ws_size,
                              hipStream_t stream) {
    const float* x   = (const float*)d_in[0];
    const float* h0  = (const float*)d_in[1];
    const float* Wih = (const float*)d_in[2];
    const float* Whh = (const float*)d_in[3];
    const float* bih = (const float*)d_in[4];
    const float* bhh = (const float*)d_in[5];
    float* out = (float*)d_out;

    xproj_kernel<<<dim3((T_N * B_N) / 64), 256, 0, stream>>>(x, Wih, bih, out);
    scan_kernel<<<dim3(B_N), 256, 0, stream>>>(Whh, bhh, h0, out);
}